// Round 1
// baseline (60.128 us; speedup 1.0000x reference)
//
#include <hip/hip_runtime.h>

// Grouped width-conv (2 groups x 12ch, k=7, same-pad, shared weights) + roll(+1,h).
// x: (1,24,112,112) f32, W: (12,12,7) f32 as W[i][oc][j]; out f32 (1,24,112,112).
// v3: one block per (h_out, g); each compute thread owns TWO output channels
// (oc, oc+6) that share the same x sliding-window reads.
//   vs v2: LDS b128 reads per output-quad 15 -> 10.5, x staged once per (h,g)
//   instead of twice (ochalf merged), barriers 448 -> 224. FMA count unchanged
//   (algorithmic floor). Risk: 224 blocks ~= 1 block/CU, 3 waves.
//   - Stage 12 input rows (h_src = h_out-1 mod 112) into LDS, 4-float zero pad
//     each side (16B-aligned reads; taps need only 3).
//   - Stage all 12 oc of W as ws[oc][i][8] (7 taps + 1 zero pad).
//   - Threads 0..167: ocp = tid/28 -> oc0=ocp, oc1=ocp+6; w_base = 4*(tid%28);
//     8 outputs each. Per i: 3x ds_read_b128 (x window) + 4x ds_read_b128 (w,
//     broadcast within ocp group) + 56 FMA.

__global__ __launch_bounds__(192) void shiftconv_kernel(
    const float* __restrict__ x, const float* __restrict__ W, float* __restrict__ out)
{
    __shared__ float xs[12 * 120];      // row p holds x value w at p = w + 4
    __shared__ float ws[12 * 12 * 8];   // [oc][i][j], j padded to 8

    const int tid   = threadIdx.x;
    const int h_out = blockIdx.x;       // 0..111
    const int g     = blockIdx.y;       // 0..1
    const int h_src = (h_out + 111) % 112;

    // ---- stage W (all 12 oc): 1152 entries = 192*6 ----
    #pragma unroll
    for (int q = 0; q < 6; ++q) {
        int idx = tid + 192 * q;        // 0..1151
        int oc  = idx / 96;             // 0..11
        int r   = idx - oc * 96;
        int i   = r >> 3;
        int j   = r & 7;
        ws[idx] = (j < 7) ? W[(i * 12 + oc) * 7 + j] : 0.0f;
    }

    // ---- stage x: 12 rows of 112 as float4 = 336 items over 192 threads (2 iters),
    //      then zero the 24 pad float4s ----
    #pragma unroll
    for (int q = 0; q < 2; ++q) {
        int idx = tid + 192 * q;        // 0..383
        if (idx < 336) {
            int i  = idx / 28;
            int c4 = (idx - i * 28) * 4;
            const float4 v = *reinterpret_cast<const float4*>(
                x + (g * 12 + i) * 12544 + h_src * 112 + c4);
            *reinterpret_cast<float4*>(&xs[i * 120 + 4 + c4]) = v;
        } else if (idx < 360) {
            int z    = idx - 336;       // 0..23
            int row  = z >> 1;
            int side = z & 1;           // 0 -> [0,4), 1 -> [116,120)
            *reinterpret_cast<float4*>(&xs[row * 120 + side * 116]) =
                make_float4(0.f, 0.f, 0.f, 0.f);
        }
    }
    __syncthreads();

    if (tid < 168) {
        const int ocp    = tid / 28;            // 0..5
        const int k      = tid - ocp * 28;
        const int w_base = k * 4;
        const int oc0    = ocp;
        const int oc1    = ocp + 6;

        float a0 = 0.f, a1 = 0.f, a2 = 0.f, a3 = 0.f;   // oc0
        float b0 = 0.f, b1 = 0.f, b2 = 0.f, b3 = 0.f;   // oc1

        #pragma unroll
        for (int i = 0; i < 12; ++i) {
            const float4 xa = *reinterpret_cast<const float4*>(&xs[i * 120 + w_base]);
            const float4 xb = *reinterpret_cast<const float4*>(&xs[i * 120 + w_base + 4]);
            const float4 xc = *reinterpret_cast<const float4*>(&xs[i * 120 + w_base + 8]);
            const float xv[12] = {xa.x, xa.y, xa.z, xa.w,
                                  xb.x, xb.y, xb.z, xb.w,
                                  xc.x, xc.y, xc.z, xc.w};

            const float4 wa0 = *reinterpret_cast<const float4*>(&ws[(oc0 * 12 + i) * 8]);
            const float4 wb0 = *reinterpret_cast<const float4*>(&ws[(oc0 * 12 + i) * 8 + 4]);
            const float4 wa1 = *reinterpret_cast<const float4*>(&ws[(oc1 * 12 + i) * 8]);
            const float4 wb1 = *reinterpret_cast<const float4*>(&ws[(oc1 * 12 + i) * 8 + 4]);
            const float wv0[7] = {wa0.x, wa0.y, wa0.z, wa0.w, wb0.x, wb0.y, wb0.z};
            const float wv1[7] = {wa1.x, wa1.y, wa1.z, wa1.w, wb1.x, wb1.y, wb1.z};

            // xs position p = w + 4; output w = w_base + m needs x at
            // w = w_base + m + j - 3 -> xv[m + j + 1]
            #pragma unroll
            for (int j = 0; j < 7; ++j) {
                a0 += xv[j + 1] * wv0[j];
                a1 += xv[j + 2] * wv0[j];
                a2 += xv[j + 3] * wv0[j];
                a3 += xv[j + 4] * wv0[j];
                b0 += xv[j + 1] * wv1[j];
                b1 += xv[j + 2] * wv1[j];
                b2 += xv[j + 3] * wv1[j];
                b3 += xv[j + 4] * wv1[j];
            }
        }

        *reinterpret_cast<float4*>(out + (g * 12 + oc0) * 12544 + h_out * 112 + w_base) =
            make_float4(a0, a1, a2, a3);
        *reinterpret_cast<float4*>(out + (g * 12 + oc1) * 12544 + h_out * 112 + w_base) =
            make_float4(b0, b1, b2, b3);
    }
}

extern "C" void kernel_launch(void* const* d_in, const int* in_sizes, int n_in,
                              void* d_out, int out_size, void* d_ws, size_t ws_size,
                              hipStream_t stream) {
    const float* x = (const float*)d_in[0];
    const float* W = (const float*)d_in[1];
    float* out     = (float*)d_out;
    shiftconv_kernel<<<dim3(112, 2), 192, 0, stream>>>(x, W, out);
}